// Round 9
// baseline (137.540 us; speedup 1.0000x reference)
//
#include <hip/hip_runtime.h>
#include <hip/hip_bf16.h>
#include <math.h>

#define S_LEN 2048
#define DIM   1024
#define NH    16
#define NKVH  4
#define HD    64
#define KVDIM 256

typedef __hip_bfloat16 bf16;
typedef __attribute__((ext_vector_type(8))) short short8;   // 8 bf16 (4 VGPRs)
typedef __attribute__((ext_vector_type(4))) float f32x4;

#define GLOBAL_AS __attribute__((address_space(1)))
#define LDS_AS    __attribute__((address_space(3)))

__device__ __forceinline__ void gload_lds16(const bf16* g, bf16* l) {
    // LDS dest = wave-uniform base + lane*16 (hardware rule).
    __builtin_amdgcn_global_load_lds((const GLOBAL_AS void*)g, (LDS_AS void*)l,
                                     16, 0, 0);
}

// Counted-drain + raw barrier (T3): at this point only the prefetch stage's
// loads are outstanding, so vmcnt(0) == "wait for next tile" without a
// compiler-forced drain before compute. Fences stop reordering.
__device__ __forceinline__ void wait_stage_and_barrier() {
    asm volatile("s_waitcnt vmcnt(0)" ::: "memory");
    __builtin_amdgcn_s_barrier();
    asm volatile("" ::: "memory");
}

// ---------------------------------------------------------------------------
// fp32 -> bf16 cast of inputs (grid.y = which). Slice 5 builds the
// COMBINE-FOLDED output weight Wo' (lambda absorbed). Slice 6 builds the
// rotary cos/sin table (bit-identical math).
// ---------------------------------------------------------------------------
__global__ __launch_bounds__(256) void cast6(
    const float* __restrict__ x,  const float* __restrict__ Wq,
    const float* __restrict__ Wk, const float* __restrict__ Wv,
    const float* __restrict__ Wg, const float* __restrict__ Wo,
    bf16* __restrict__ xb,  bf16* __restrict__ Wqb,
    bf16* __restrict__ Wkb, bf16* __restrict__ Wvb,
    bf16* __restrict__ Wgb, bf16* __restrict__ Wob,
    float* __restrict__ rc, float* __restrict__ rs,
    const float* __restrict__ lp) {
    if (blockIdx.y == 6) {
        const int idx = blockIdx.x * 256 + threadIdx.x;
        if (idx < S_LEN * 32) {
            const int s = idx >> 5, i = idx & 31;
            float af  = (float)(((double)(2 * i) / 64.0) * 3.14159265358979323846);
            float ang = (float)s * af;
            float radius = 1.0f / (1.0f + 0.01f * (float)s);
            rc[idx] = radius * (float)cos((double)ang);
            rs[idx] = radius * (float)sin((double)ang);
        }
        return;
    }
    if (blockIdx.y == 5) {                 // Wo' build (combine folded)
        for (int i = (blockIdx.x * 256 + threadIdx.x) * 4; i < DIM * DIM;
             i += gridDim.x * 1024) {
            const int n = i >> 10, c = i & (DIM - 1);
            const int h = c >> 6, half = (c >> 5) & 1, d = c & 31;
            const float* base = Wo + (size_t)n * DIM + h * 64 + d;
            float4 w1 = *(const float4*)(base);
            float4 w2 = *(const float4*)(base + 32);
            const float lam = lp[h];
            float4 r;
            if (half == 0) {
                r.x = w1.x + w2.x; r.y = w1.y + w2.y;
                r.z = w1.z + w2.z; r.w = w1.w + w2.w;
            } else {
                r.x = lam * (w2.x - w1.x); r.y = lam * (w2.y - w1.y);
                r.z = lam * (w2.z - w1.z); r.w = lam * (w2.w - w1.w);
            }
            Wob[i]     = __float2bfloat16(r.x);
            Wob[i + 1] = __float2bfloat16(r.y);
            Wob[i + 2] = __float2bfloat16(r.z);
            Wob[i + 3] = __float2bfloat16(r.w);
        }
        return;
    }
    const float* s; bf16* d; int n;
    switch (blockIdx.y) {
        case 0: s = x;  d = xb;  n = S_LEN * DIM; break;
        case 1: s = Wq; d = Wqb; n = DIM * DIM;   break;
        case 2: s = Wk; d = Wkb; n = KVDIM * DIM; break;
        case 3: s = Wv; d = Wvb; n = KVDIM * DIM; break;
        default: s = Wg; d = Wgb; n = KVDIM * DIM; break;
    }
    for (int i = (blockIdx.x * 256 + threadIdx.x) * 4; i < n; i += gridDim.x * 1024) {
        float4 v = *(const float4*)(s + i);
        d[i]     = __float2bfloat16(v.x);
        d[i + 1] = __float2bfloat16(v.y);
        d[i + 2] = __float2bfloat16(v.z);
        d[i + 3] = __float2bfloat16(v.w);
    }
}

// ---------------------------------------------------------------------------
// R5-verified 64x64 GEMM core (single-buffered; gload_lds staging; XOR
// swizzle both sides). Used by gemm_out.
// ---------------------------------------------------------------------------
__device__ __forceinline__ void gemm_core(
    const bf16* __restrict__ A, const bf16* __restrict__ B,
    float* __restrict__ C, int bm, int bn, int N, int K) {
    __shared__ bf16 As[64 * 64];
    __shared__ bf16 Bs[64 * 64];
    const int tid  = threadIdx.x;
    const int w    = tid >> 6;
    const int lane = tid & 63;
    const int quad = lane >> 4;
    const int lm   = lane & 15;
    const int srow = tid >> 3;
    const int sseg = (tid & 7) ^ (srow & 7);
    const bf16* a0p = A + (size_t)(bm + srow) * K + (sseg << 3);
    const bf16* a1p = a0p + (size_t)32 * K;
    const bf16* b0p = B + (size_t)(bn + srow) * K + (sseg << 3);
    const bf16* b1p = b0p + (size_t)32 * K;
    bf16* ldsA = As + w * 512;
    bf16* ldsB = Bs + w * 512;

    f32x4 acc[4] = {};
    const int ra  = w * 16 + lm;
    const int rax = ra & 7;
    const int aoff0 = ra * 64 + (((quad    ) ^ rax) << 3);
    const int aoff1 = ra * 64 + (((quad + 4) ^ rax) << 3);
    const int rbx = lm & 7;
    const int boff0 = lm * 64 + (((quad    ) ^ rbx) << 3);
    const int boff1 = lm * 64 + (((quad + 4) ^ rbx) << 3);

    for (int k0 = 0; k0 < K; k0 += 64) {
        gload_lds16(a0p + k0, ldsA);
        gload_lds16(a1p + k0, ldsA + 2048);
        gload_lds16(b0p + k0, ldsB);
        gload_lds16(b1p + k0, ldsB + 2048);
        __syncthreads();
        short8 a0 = *(const short8*)&As[aoff0];
        short8 a1 = *(const short8*)&As[aoff1];
        #pragma unroll
        for (int t = 0; t < 4; ++t) {
            short8 b0 = *(const short8*)&Bs[boff0 + t * 16 * 64];
            short8 b1 = *(const short8*)&Bs[boff1 + t * 16 * 64];
            acc[t] = __builtin_amdgcn_mfma_f32_16x16x32_bf16(a0, b0, acc[t], 0, 0, 0);
            acc[t] = __builtin_amdgcn_mfma_f32_16x16x32_bf16(a1, b1, acc[t], 0, 0, 0);
        }
        __syncthreads();
    }
    const int r0 = bm + w * 16 + quad * 4;
    #pragma unroll
    for (int t = 0; t < 4; ++t) {
        const int col = bn + t * 16 + lm;
        #pragma unroll
        for (int i = 0; i < 4; ++i)
            C[(size_t)(r0 + i) * N + col] = acc[t][i];
    }
}

__global__ __launch_bounds__(256) void gemm_out(
    const bf16* __restrict__ Yb, const bf16* __restrict__ Wob,
    float* __restrict__ C) {
    gemm_core(Yb, Wob, C, blockIdx.y * 64, blockIdx.x * 64, DIM, DIM);
}

// ---------------------------------------------------------------------------
// FUSED Q/K/V/G projection + postproc, two cores in one dispatch:
//  blocks 0..159  : 128x128 / BK=64 / T3 2-phase double-buffered core for
//                   Q (col 0..7) and K (col 8,9) tiles. 4 waves in 2x2; each
//                   wave owns a 64-col head quadrant -> the R3 RMSNorm/rotary
//                   epilogue carries over verbatim (partner frag nr^2, same
//                   reduction grouping -> bit-identical). 32 MFMA per K-step
//                   per wave from 16 ds_read_b128; LDS 64 KB -> 2 blocks/CU.
//  blocks 160..287: verified 64x64 single-buffer VG core (V,G tiles + gate).
// Same-dispatch mixing lets VG blocks fill CUs during the QK tail.
// ---------------------------------------------------------------------------
__global__ __launch_bounds__(256) void gemm_qkvg_post(
    const bf16* __restrict__ xb,  const bf16* __restrict__ Wqb,
    const bf16* __restrict__ Wkb, const bf16* __restrict__ Wvb,
    const bf16* __restrict__ Wgb,
    bf16* __restrict__ Qb, bf16* __restrict__ Kpk, bf16* __restrict__ Vpk,
    const float* __restrict__ qgain,
    const float* __restrict__ rc, const float* __restrict__ rs) {
    __shared__ char pool[65536];
    const int bx   = blockIdx.x;
    const int tid  = threadIdx.x;
    const int w    = tid >> 6;
    const int lane = tid & 63;
    const int quad = lane >> 4;
    const int lm   = lane & 15;
    const int srow32 = tid >> 3;            // 0..31
    const int sseg   = (tid & 7) ^ (srow32 & 7);

    if (bx < 160) {
        // ---------------- 128x128 QK core ----------------
        const int col = bx % 10;
        const int bm  = (bx / 10) * 128;
        const bool isQ = (col < 8);
        const bf16* Bw = isQ ? Wqb : Wkb;
        const int bn   = isQ ? col * 128 : (col - 8) * 128;

        bf16* As = (bf16*)pool;             // [2][128*64] shorts (32 KB)
        bf16* Bs = (bf16*)(pool + 32768);   // [2][128*64]
        const int wr = w >> 1, wc = w & 1;

        // staging: dest byte = tid*16 + i*4096 -> row = tid/8 + i*32,
        // seg = tid&7, source seg pre-XOR'd with row&7 (rule #21).
        const bf16* aS = xb + (size_t)(bm + srow32) * DIM + (sseg << 3);
        const bf16* bS = Bw + (size_t)(bn + srow32) * DIM + (sseg << 3);
        const int wo = w * 512;             // wave-uniform dest (shorts)

        f32x4 acc[4][4] = {};
        int aoff[4][2], boff[4][2];
        #pragma unroll
        for (int mr = 0; mr < 4; ++mr) {
            const int ra = wr * 64 + mr * 16 + lm, rax = ra & 7;
            aoff[mr][0] = ra * 64 + (((quad    ) ^ rax) << 3);
            aoff[mr][1] = ra * 64 + (((quad + 4) ^ rax) << 3);
        }
        #pragma unroll
        for (int nr = 0; nr < 4; ++nr) {
            const int rb = wc * 64 + nr * 16 + lm, rbx = rb & 7;
            boff[nr][0] = rb * 64 + (((quad    ) ^ rbx) << 3);
            boff[nr][1] = rb * 64 + (((quad + 4) ^ rbx) << 3);
        }

        // prologue: stage tile 0 into buf 0
        #pragma unroll
        for (int i = 0; i < 4; ++i) {
            gload_lds16(aS + (size_t)(i * 32) * DIM, As + i * 2048 + wo);
            gload_lds16(bS + (size_t)(i * 32) * DIM, Bs + i * 2048 + wo);
        }
        wait_stage_and_barrier();

        const int nt = DIM / 64;            // 16
        for (int t = 0; t < nt; ++t) {
            const int cur = t & 1;
            if (t + 1 < nt) {
                const int k0 = (t + 1) << 6;
                const int nb = cur ^ 1;
                #pragma unroll
                for (int i = 0; i < 4; ++i) {
                    gload_lds16(aS + (size_t)(i * 32) * DIM + k0,
                                As + nb * 8192 + i * 2048 + wo);
                    gload_lds16(bS + (size_t)(i * 32) * DIM + k0,
                                Bs + nb * 8192 + i * 2048 + wo);
                }
            }
            const bf16* Ac = As + cur * 8192;
            const bf16* Bc = Bs + cur * 8192;
            #pragma unroll
            for (int kh = 0; kh < 2; ++kh) {
                short8 af[4], bfr[4];
                #pragma unroll
                for (int mr = 0; mr < 4; ++mr) af[mr]  = *(const short8*)&Ac[aoff[mr][kh]];
                #pragma unroll
                for (int nr = 0; nr < 4; ++nr) bfr[nr] = *(const short8*)&Bc[boff[nr][kh]];
                #pragma unroll
                for (int mr = 0; mr < 4; ++mr)
                    #pragma unroll
                    for (int nr = 0; nr < 4; ++nr)
                        acc[mr][nr] = __builtin_amdgcn_mfma_f32_16x16x32_bf16(
                            af[mr], bfr[nr], acc[mr][nr], 0, 0, 0);
            }
            if (t + 1 < nt) wait_stage_and_barrier();
        }

        // epilogue: RMSNorm + rotary (+gain) per wave-quadrant head
        const float gain = isQ ? qgain[col * 2 + wc] : 1.0f;
        float rr[4][4];
        #pragma unroll
        for (int mr = 0; mr < 4; ++mr)
            #pragma unroll
            for (int i = 0; i < 4; ++i) {
                float v0 = acc[mr][0][i] * acc[mr][0][i] + acc[mr][2][i] * acc[mr][2][i];
                float v1 = acc[mr][1][i] * acc[mr][1][i] + acc[mr][3][i] * acc[mr][3][i];
                float ssv = v0 + v1;
                ssv += __shfl_xor(ssv, 8);
                ssv += __shfl_xor(ssv, 4);
                ssv += __shfl_xor(ssv, 2);
                ssv += __shfl_xor(ssv, 1);
                rr[mr][i] = rsqrtf(ssv * (1.0f/64.0f) + 1.1920928955078125e-7f);
            }
        #pragma unroll
        for (int mr = 0; mr < 4; ++mr) {
            const int r0 = bm + wr * 64 + mr * 16 + quad * 4;
            #pragma unroll
            for (int nr = 0; nr < 4; ++nr) {
                const int d = nr * 16 + lm;
                #pragma unroll
                for (int i = 0; i < 4; ++i) {
                    const int s = r0 + i;
                    float n  = acc[mr][nr][i]     * rr[mr][i];
                    float no = acc[mr][nr ^ 2][i] * rr[mr][i];
                    const int ri = s * 32 + (d & 31);
                    float c = rc[ri], sn = rs[ri];
                    float val = (nr < 2) ? (n * c + no * sn) * gain
                                         : (n * c + -no * sn) * gain;
                    if (isQ) {
                        Qb[(size_t)s * DIM + (col * 2 + wc) * 64 + d] =
                            __float2bfloat16(val);
                    } else {
                        const int kvh = (col - 8) * 2 + wc;
                        const int half = d >> 5, d32 = d & 31;
                        const size_t ki = (((((size_t)(kvh*2 + half)*64 + (s>>5))*2
                                             + ((s&31)>>4))*64)
                                           + (d32>>3)*16 + (s&15))*8 + (d32&7);
                        Kpk[ki] = __float2bfloat16(val);
                    }
                }
            }
        }
        return;
    }

    // ---------------- 64x64 VG core (verified) ----------------
    const int idx = bx - 160;               // 0..127
    const int vcx = idx >> 5;               // 0..3 (64-col V/G tile)
    const int bm  = (idx & 31) * 64;
    const int bn  = vcx * 64;

    bf16* As = (bf16*)pool;                 // 8 KB each
    bf16* Bs = (bf16*)(pool + 8192);
    bf16* Gs = (bf16*)(pool + 16384);

    const bf16* a0p = xb  + (size_t)(bm + srow32) * DIM + (sseg << 3);
    const bf16* a1p = a0p + (size_t)32 * DIM;
    const bf16* b0p = Wvb + (size_t)(bn + srow32) * DIM + (sseg << 3);
    const bf16* b1p = b0p + (size_t)32 * DIM;
    const bf16* g0p = Wgb + (size_t)(bn + srow32) * DIM + (sseg << 3);
    const bf16* g1p = g0p + (size_t)32 * DIM;
    bf16* ldsA = As + w * 512;
    bf16* ldsB = Bs + w * 512;
    bf16* ldsG = Gs + w * 512;

    f32x4 acc[4]  = {};
    f32x4 acc2[4] = {};
    const int ra  = w * 16 + lm;
    const int rax = ra & 7;
    const int aoff0 = ra * 64 + (((quad    ) ^ rax) << 3);
    const int aoff1 = ra * 64 + (((quad + 4) ^ rax) << 3);
    const int rbx = lm & 7;
    const int boff0 = lm * 64 + (((quad    ) ^ rbx) << 3);
    const int boff1 = lm * 64 + (((quad + 4) ^ rbx) << 3);

    for (int k0 = 0; k0 < DIM; k0 += 64) {
        gload_lds16(a0p + k0, ldsA);
        gload_lds16(a1p + k0, ldsA + 2048);
        gload_lds16(b0p + k0, ldsB);
        gload_lds16(b1p + k0, ldsB + 2048);
        gload_lds16(g0p + k0, ldsG);
        gload_lds16(g1p + k0, ldsG + 2048);
        __syncthreads();
        short8 a0 = *(const short8*)&As[aoff0];
        short8 a1 = *(const short8*)&As[aoff1];
        #pragma unroll
        for (int t = 0; t < 4; ++t) {
            short8 b0 = *(const short8*)&Bs[boff0 + t * 16 * 64];
            short8 b1 = *(const short8*)&Bs[boff1 + t * 16 * 64];
            acc[t] = __builtin_amdgcn_mfma_f32_16x16x32_bf16(a0, b0, acc[t], 0, 0, 0);
            acc[t] = __builtin_amdgcn_mfma_f32_16x16x32_bf16(a1, b1, acc[t], 0, 0, 0);
        }
        #pragma unroll
        for (int t = 0; t < 4; ++t) {
            short8 g0 = *(const short8*)&Gs[boff0 + t * 16 * 64];
            short8 g1 = *(const short8*)&Gs[boff1 + t * 16 * 64];
            acc2[t] = __builtin_amdgcn_mfma_f32_16x16x32_bf16(a0, g0, acc2[t], 0, 0, 0);
            acc2[t] = __builtin_amdgcn_mfma_f32_16x16x32_bf16(a1, g1, acc2[t], 0, 0, 0);
        }
        __syncthreads();
    }

    const int r0 = bm + w * 16 + quad * 4;
    const int kvh = vcx;
    #pragma unroll
    for (int t = 0; t < 4; ++t) {
        const int d = t * 16 + lm;
        const int half = d >> 5, d32 = d & 31;
        #pragma unroll
        for (int i = 0; i < 4; ++i) {
            const int s = r0 + i;
            float val = acc[t][i] / (1.0f + __expf(-acc2[t][i]));
            const size_t vi = (((((size_t)(kvh*2 + half)*64 + (s>>5))*2 + (d32>>4))*64)
                               + ((s&31)>>3)*16 + (d32&15))*8 + (s&7);
            Vpk[vi] = __float2bfloat16(val);
        }
    }
}

// ---------------------------------------------------------------------------
// MFMA flash attention v5b (R8-verified): 4-wave k-split, LDS P round-trip,
// tile-uniform mask skip, setprio around MFMA pairs, linear merge.
// ---------------------------------------------------------------------------
__global__ __launch_bounds__(256, 8) void attn_mfma(
    const bf16* __restrict__ Qb, const bf16* __restrict__ Kpk,
    const bf16* __restrict__ Vpk, bf16* __restrict__ Yab) {
    __shared__ short PW[4][640];          // per-wave P round-trip buffers
    __shared__ float RED[3][64][13];      // waves 1-3 partials (padded rows)
    const int id    = blockIdx.x;
    const int qtile = 127 - (id >> 5);    // heavy first
    const int hh    = id & 31;
    const int h     = hh >> 1;
    const int half  = hh & 1;
    const int kvh   = h >> 2;
    const int tid   = threadIdx.x;
    const int wid   = tid >> 6;
    const int lane  = tid & 63;
    const int quad  = lane >> 4;
    const int m     = lane & 15;
    bf16* PWb = (bf16*)PW[wid];

    const int qrow = qtile * 16 + m;
    short8 qf = *(const short8*)(Qb + (size_t)qrow * DIM + h * HD + half * 32 + quad * 8);

    const bf16* kbase = Kpk + (size_t)(kvh * 2 + half) * 64 * 1024 + lane * 8;
    const bf16* vbase = Vpk + (size_t)(kvh * 2 + half) * 64 * 1024 + lane * 8;

    f32x4 o0 = {}, o1 = {};
    float lpart[4] = {0.f, 0.f, 0.f, 0.f};
    const float scale = 0.17677669529663687f;   // 1/sqrt(32)
    const int rbase = qtile * 16 + quad * 4;
    const int nkt = (qtile >> 1) + 1;

    for (int kb = wid; kb < nkt; kb += 4) {
        short8 kf0 = *(const short8*)(kbase + kb * 1024);
        short8 kf1 = *(const short8*)(kbase + kb * 1024 + 512);
        f32x4 s0 = {}, s1 = {};
        __builtin_amdgcn_s_setprio(1);
        s0 = __builtin_amdgcn_mfma_f32_16x16x32_bf16(qf, kf0, s0, 0, 0, 0);
        s1 = __builtin_amdgcn_mfma_f32_16x16x32_bf16(qf, kf1, s1, 0, 0, 0);
        __builtin_amdgcn_s_setprio(0);
        short8 vt0 = *(const short8*)(vbase + kb * 1024);
        short8 vt1 = *(const short8*)(vbase + kb * 1024 + 512);

        float p0v[4], p1v[4];
        if (kb * 32 + 31 <= qtile * 16) {           // fully unmasked tile
            #pragma unroll
            for (int r = 0; r < 4; ++r) {
                p0v[r] = __expf(s0[r] * scale);
                p1v[r] = __expf(s1[r] * scale);
            }
        } else {                                    // diagonal straddle
            const int kg = kb * 32 + m;
            #pragma unroll
            for (int r = 0; r < 4; ++r) {
                const int rg = rbase + r;
                p0v[r] = (kg > rg)      ? 0.f : __expf(s0[r] * scale);
                p1v[r] = (kg + 16 > rg) ? 0.f : __expf(s1[r] * scale);
            }
        }
        #pragma unroll
        for (int r = 0; r < 4; ++r) {
            lpart[r] += p0v[r] + p1v[r];
            PWb[(quad * 4 + r) * 40 + m]      = __float2bfloat16(p0v[r]);
            PWb[(quad * 4 + r) * 40 + 16 + m] = __float2bfloat16(p1v[r]);
        }
        asm volatile("s_waitcnt lgkmcnt(0)" ::: "memory");
        short8 pf = *(const short8*)&PW[wid][m * 40 + quad * 8];
        __builtin_amdgcn_s_setprio(1);
        o0 = __builtin_amdgcn_mfma_f32_16x16x32_bf16(pf, vt0, o0, 0, 0, 0);
        o1 = __builtin_amdgcn_mfma_f32_16x16x32_bf16(pf, vt1, o1, 0, 0, 0);
        __builtin_amdgcn_s_setprio(0);
    }

    // cross-wave merge: waves 1-3 park partials; wave 0 reduces + writes.
    if (wid > 0) {
        float* rp = &RED[wid - 1][lane][0];
        #pragma unroll
        for (int r = 0; r < 4; ++r) {
            rp[r]     = o0[r];
            rp[4 + r] = o1[r];
            rp[8 + r] = lpart[r];
        }
    }
    __syncthreads();
    if (wid == 0) {
        #pragma unroll
        for (int wv = 0; wv < 3; ++wv) {
            const float* rp = &RED[wv][lane][0];
            #pragma unroll
            for (int r = 0; r < 4; ++r) {
                o0[r]     += rp[r];
                o1[r]     += rp[4 + r];
                lpart[r]  += rp[8 + r];
            }
        }
        #pragma unroll
        for (int r = 0; r < 4; ++r) {
            float v = lpart[r];
            v += __shfl_xor(v, 1);
            v += __shfl_xor(v, 2);
            v += __shfl_xor(v, 4);
            v += __shfl_xor(v, 8);
            lpart[r] = 1.f / v;
        }
        #pragma unroll
        for (int r = 0; r < 4; ++r) {
            bf16* op = Yab + (size_t)(rbase + r) * DIM + h * HD + half * 32;
            op[m]      = __float2bfloat16(o0[r] * lpart[r]);
            op[16 + m] = __float2bfloat16(o1[r] * lpart[r]);
        }
    }
}

// ---------------------------------------------------------------------------
// Workspace (31.5 MB):
//  0-4    Qb bf16 (step1 w, step2 r)
//  8-9    Kpk bf16 | 9-10 Vpk bf16 (step1 w, step2 r)
//  14-14.5 rc/rs rotary table (step0 w, step1 r; dead after)
//  14-18  Yab bf16 attn out, a_raw layout (step2 w, step3 r; overlays rc/rs)
//  22-26  xb bf16 (step0 w, step1 r)
//  26-28  Wqb | 28-28.5 Wkb | 28.5-29 Wvb | 29-29.5 Wgb | 29.5-31.5 Wob'
// ---------------------------------------------------------------------------
extern "C" void kernel_launch(void* const* d_in, const int* in_sizes, int n_in,
                              void* d_out, int out_size, void* d_ws, size_t ws_size,
                              hipStream_t stream) {
    const float* x  = (const float*)d_in[0];
    const float* Wq = (const float*)d_in[1];
    const float* Wk = (const float*)d_in[2];
    const float* Wv = (const float*)d_in[3];
    const float* Wg = (const float*)d_in[4];
    const float* Wo = (const float*)d_in[5];
    const float* qg = (const float*)d_in[6];
    const float* lp = (const float*)d_in[7];
    float* out = (float*)d_out;

    char* ws = (char*)d_ws;
    bf16* Qb   = (bf16*)ws;
    bf16* Kpk  = (bf16*)(ws + (8u << 20));
    bf16* Vpk  = (bf16*)(ws + (9u << 20));
    float* rc  = (float*)(ws + (14u << 20));
    float* rs  = (float*)(ws + (14u << 20) + (256u << 10));
    bf16* Yab  = (bf16*)(ws + (14u << 20));    // overlays dead rc/rs
    bf16* xb   = (bf16*)(ws + (22u << 20));
    bf16* Wqb  = (bf16*)(ws + (26u << 20));
    bf16* Wkb  = (bf16*)(ws + (28u << 20));
    bf16* Wvb  = (bf16*)(ws + (28u << 20) + (512u << 10));
    bf16* Wgb  = (bf16*)(ws + (29u << 20));
    bf16* Wob  = (bf16*)(ws + (29u << 20) + (512u << 10));

    // 0. Cast inputs to bf16 + combine-folded Wo' + rotary table
    cast6<<<dim3(512, 7), 256, 0, stream>>>(x, Wq, Wk, Wv, Wg, Wo,
                                            xb, Wqb, Wkb, Wvb, Wgb, Wob,
                                            rc, rs, lp);

    // 1. Fused Q/K/V/G projection + epilogue: 160 QK blocks (128^2 dbuf)
    //    + 128 VG blocks (64^2), one dispatch.
    gemm_qkvg_post<<<dim3(288), 256, 0, stream>>>(
        xb, Wqb, Wkb, Wvb, Wgb, Qb, Kpk, Vpk, qg, rc, rs);

    // 2. MFMA flash attention (R8-verified)
    attn_mfma<<<4096, 256, 0, stream>>>(Qb, Kpk, Vpk, Yab);

    // 3. Combine-folded output projection (verified 64^2 core)
    gemm_out<<<dim3(DIM/64, S_LEN/64), 256, 0, stream>>>(Yab, Wob, out);
}

// Round 10
// 136.801 us; speedup vs baseline: 1.0054x; 1.0054x over previous
//
#include <hip/hip_runtime.h>
#include <hip/hip_bf16.h>
#include <math.h>

#define S_LEN 2048
#define DIM   1024
#define NH    16
#define NKVH  4
#define HD    64
#define KVDIM 256

typedef __hip_bfloat16 bf16;
typedef __attribute__((ext_vector_type(8))) short short8;   // 8 bf16 (4 VGPRs)
typedef __attribute__((ext_vector_type(4))) float f32x4;

#define GLOBAL_AS __attribute__((address_space(1)))
#define LDS_AS    __attribute__((address_space(3)))

__device__ __forceinline__ void gload_lds16(const bf16* g, bf16* l) {
    // LDS dest = wave-uniform base + lane*16 (hardware rule).
    __builtin_amdgcn_global_load_lds((const GLOBAL_AS void*)g, (LDS_AS void*)l,
                                     16, 0, 0);
}

// ---------------------------------------------------------------------------
// fp32 -> bf16 cast of inputs (grid.y = which). Slice 5 builds the
// COMBINE-FOLDED output weight Wo' (lambda absorbed):
//   Wo'[n, h*64+d]    = Wo[n,h*64+d] + Wo[n,h*64+32+d]        (a1 slot)
//   Wo'[n, h*64+32+d] = lam_h*(Wo[n,h*64+32+d] - Wo[n,h*64+d]) (a2 slot)
// Slice 6 builds the rotary cos/sin table (bit-identical math).
// ---------------------------------------------------------------------------
__global__ __launch_bounds__(256) void cast6(
    const float* __restrict__ x,  const float* __restrict__ Wq,
    const float* __restrict__ Wk, const float* __restrict__ Wv,
    const float* __restrict__ Wg, const float* __restrict__ Wo,
    bf16* __restrict__ xb,  bf16* __restrict__ Wqb,
    bf16* __restrict__ Wkb, bf16* __restrict__ Wvb,
    bf16* __restrict__ Wgb, bf16* __restrict__ Wob,
    float* __restrict__ rc, float* __restrict__ rs,
    const float* __restrict__ lp) {
    if (blockIdx.y == 6) {
        const int idx = blockIdx.x * 256 + threadIdx.x;
        if (idx < S_LEN * 32) {
            const int s = idx >> 5, i = idx & 31;
            float af  = (float)(((double)(2 * i) / 64.0) * 3.14159265358979323846);
            float ang = (float)s * af;
            float radius = 1.0f / (1.0f + 0.01f * (float)s);
            rc[idx] = radius * (float)cos((double)ang);
            rs[idx] = radius * (float)sin((double)ang);
        }
        return;
    }
    if (blockIdx.y == 5) {                 // Wo' build (combine folded)
        for (int i = (blockIdx.x * 256 + threadIdx.x) * 4; i < DIM * DIM;
             i += gridDim.x * 1024) {
            const int n = i >> 10, c = i & (DIM - 1);
            const int h = c >> 6, half = (c >> 5) & 1, d = c & 31;
            const float* base = Wo + (size_t)n * DIM + h * 64 + d;
            float4 w1 = *(const float4*)(base);
            float4 w2 = *(const float4*)(base + 32);
            const float lam = lp[h];
            float4 r;
            if (half == 0) {
                r.x = w1.x + w2.x; r.y = w1.y + w2.y;
                r.z = w1.z + w2.z; r.w = w1.w + w2.w;
            } else {
                r.x = lam * (w2.x - w1.x); r.y = lam * (w2.y - w1.y);
                r.z = lam * (w2.z - w1.z); r.w = lam * (w2.w - w1.w);
            }
            Wob[i]     = __float2bfloat16(r.x);
            Wob[i + 1] = __float2bfloat16(r.y);
            Wob[i + 2] = __float2bfloat16(r.z);
            Wob[i + 3] = __float2bfloat16(r.w);
        }
        return;
    }
    const float* s; bf16* d; int n;
    switch (blockIdx.y) {
        case 0: s = x;  d = xb;  n = S_LEN * DIM; break;
        case 1: s = Wq; d = Wqb; n = DIM * DIM;   break;
        case 2: s = Wk; d = Wkb; n = KVDIM * DIM; break;
        case 3: s = Wv; d = Wvb; n = KVDIM * DIM; break;
        default: s = Wg; d = Wgb; n = KVDIM * DIM; break;
    }
    for (int i = (blockIdx.x * 256 + threadIdx.x) * 4; i < n; i += gridDim.x * 1024) {
        float4 v = *(const float4*)(s + i);
        d[i]     = __float2bfloat16(v.x);
        d[i + 1] = __float2bfloat16(v.y);
        d[i + 2] = __float2bfloat16(v.z);
        d[i + 3] = __float2bfloat16(v.w);
    }
}

// ---------------------------------------------------------------------------
// R5-verified 64x64 GEMM core (single-buffered; gload_lds staging; XOR
// swizzle both sides). GEMM structure is FROZEN: R2/R6/R9 all showed larger
// tiles / dbuf lose to occupancy at this problem size (m102 plateau).
// ---------------------------------------------------------------------------
__device__ __forceinline__ void gemm_core(
    const bf16* __restrict__ A, const bf16* __restrict__ B,
    float* __restrict__ C, int bm, int bn, int N, int K) {
    __shared__ bf16 As[64 * 64];
    __shared__ bf16 Bs[64 * 64];
    const int tid  = threadIdx.x;
    const int w    = tid >> 6;
    const int lane = tid & 63;
    const int quad = lane >> 4;
    const int lm   = lane & 15;
    const int srow = tid >> 3;
    const int sseg = (tid & 7) ^ (srow & 7);
    const bf16* a0p = A + (size_t)(bm + srow) * K + (sseg << 3);
    const bf16* a1p = a0p + (size_t)32 * K;
    const bf16* b0p = B + (size_t)(bn + srow) * K + (sseg << 3);
    const bf16* b1p = b0p + (size_t)32 * K;
    bf16* ldsA = As + w * 512;
    bf16* ldsB = Bs + w * 512;

    f32x4 acc[4] = {};
    const int ra  = w * 16 + lm;
    const int rax = ra & 7;
    const int aoff0 = ra * 64 + (((quad    ) ^ rax) << 3);
    const int aoff1 = ra * 64 + (((quad + 4) ^ rax) << 3);
    const int rbx = lm & 7;
    const int boff0 = lm * 64 + (((quad    ) ^ rbx) << 3);
    const int boff1 = lm * 64 + (((quad + 4) ^ rbx) << 3);

    for (int k0 = 0; k0 < K; k0 += 64) {
        gload_lds16(a0p + k0, ldsA);
        gload_lds16(a1p + k0, ldsA + 2048);
        gload_lds16(b0p + k0, ldsB);
        gload_lds16(b1p + k0, ldsB + 2048);
        __syncthreads();
        short8 a0 = *(const short8*)&As[aoff0];
        short8 a1 = *(const short8*)&As[aoff1];
        #pragma unroll
        for (int t = 0; t < 4; ++t) {
            short8 b0 = *(const short8*)&Bs[boff0 + t * 16 * 64];
            short8 b1 = *(const short8*)&Bs[boff1 + t * 16 * 64];
            acc[t] = __builtin_amdgcn_mfma_f32_16x16x32_bf16(a0, b0, acc[t], 0, 0, 0);
            acc[t] = __builtin_amdgcn_mfma_f32_16x16x32_bf16(a1, b1, acc[t], 0, 0, 0);
        }
        __syncthreads();
    }
    const int r0 = bm + w * 16 + quad * 4;
    #pragma unroll
    for (int t = 0; t < 4; ++t) {
        const int col = bn + t * 16 + lm;
        #pragma unroll
        for (int i = 0; i < 4; ++i)
            C[(size_t)(r0 + i) * N + col] = acc[t][i];
    }
}

__global__ __launch_bounds__(256) void gemm_out(
    const bf16* __restrict__ Yb, const bf16* __restrict__ Wob,
    float* __restrict__ C) {
    gemm_core(Yb, Wob, C, blockIdx.y * 64, blockIdx.x * 64, DIM, DIM);
}

// ---------------------------------------------------------------------------
// FUSED Q/K/V/G projection + postproc (R3/R5/R8-verified single-buffer core).
// grid.x: 0-3 VG (heavy first), 4-7 K, 8-23 Q.
// ---------------------------------------------------------------------------
__global__ __launch_bounds__(256) void gemm_qkvg_post(
    const bf16* __restrict__ xb,  const bf16* __restrict__ Wqb,
    const bf16* __restrict__ Wkb, const bf16* __restrict__ Wvb,
    const bf16* __restrict__ Wgb,
    bf16* __restrict__ Qb, bf16* __restrict__ Kpk, bf16* __restrict__ Vpk,
    const float* __restrict__ qgain,
    const float* __restrict__ rc, const float* __restrict__ rs) {
    __shared__ bf16 As[64 * 64];
    __shared__ bf16 Bs[64 * 64];
    __shared__ bf16 Gs[64 * 64];
    const int cx = blockIdx.x;
    const int bm = blockIdx.y * 64;
    const int tid  = threadIdx.x;
    const int w    = tid >> 6;
    const int lane = tid & 63;
    const int quad = lane >> 4;
    const int lm   = lane & 15;
    const int srow = tid >> 3;
    const int sseg = (tid & 7) ^ (srow & 7);

    int mode, bn;                       // 0=Q, 1=K, 2=VG (block-uniform)
    const bf16 *B0, *B1;
    if (cx < 4)      { mode = 2; bn = cx * 64;        B0 = Wvb; B1 = Wgb; }
    else if (cx < 8) { mode = 1; bn = (cx - 4) * 64;  B0 = Wkb; B1 = Wkb; }
    else             { mode = 0; bn = (cx - 8) * 64;  B0 = Wqb; B1 = Wqb; }

    const bf16* a0p = xb + (size_t)(bm + srow) * DIM + (sseg << 3);
    const bf16* a1p = a0p + (size_t)32 * DIM;
    const bf16* b0p = B0 + (size_t)(bn + srow) * DIM + (sseg << 3);
    const bf16* b1p = b0p + (size_t)32 * DIM;
    const bf16* g0p = B1 + (size_t)(bn + srow) * DIM + (sseg << 3);
    const bf16* g1p = g0p + (size_t)32 * DIM;
    bf16* ldsA = As + w * 512;
    bf16* ldsB = Bs + w * 512;
    bf16* ldsG = Gs + w * 512;

    f32x4 acc[4]  = {};
    f32x4 acc2[4] = {};
    const int ra  = w * 16 + lm;
    const int rax = ra & 7;
    const int aoff0 = ra * 64 + (((quad    ) ^ rax) << 3);
    const int aoff1 = ra * 64 + (((quad + 4) ^ rax) << 3);
    const int rbx = lm & 7;
    const int boff0 = lm * 64 + (((quad    ) ^ rbx) << 3);
    const int boff1 = lm * 64 + (((quad + 4) ^ rbx) << 3);

    for (int k0 = 0; k0 < DIM; k0 += 64) {
        gload_lds16(a0p + k0, ldsA);
        gload_lds16(a1p + k0, ldsA + 2048);
        gload_lds16(b0p + k0, ldsB);
        gload_lds16(b1p + k0, ldsB + 2048);
        if (mode == 2) {
            gload_lds16(g0p + k0, ldsG);
            gload_lds16(g1p + k0, ldsG + 2048);
        }
        __syncthreads();
        short8 a0 = *(const short8*)&As[aoff0];
        short8 a1 = *(const short8*)&As[aoff1];
        #pragma unroll
        for (int t = 0; t < 4; ++t) {
            short8 b0 = *(const short8*)&Bs[boff0 + t * 16 * 64];
            short8 b1 = *(const short8*)&Bs[boff1 + t * 16 * 64];
            acc[t] = __builtin_amdgcn_mfma_f32_16x16x32_bf16(a0, b0, acc[t], 0, 0, 0);
            acc[t] = __builtin_amdgcn_mfma_f32_16x16x32_bf16(a1, b1, acc[t], 0, 0, 0);
        }
        if (mode == 2) {
            #pragma unroll
            for (int t = 0; t < 4; ++t) {
                short8 g0 = *(const short8*)&Gs[boff0 + t * 16 * 64];
                short8 g1 = *(const short8*)&Gs[boff1 + t * 16 * 64];
                acc2[t] = __builtin_amdgcn_mfma_f32_16x16x32_bf16(a0, g0, acc2[t], 0, 0, 0);
                acc2[t] = __builtin_amdgcn_mfma_f32_16x16x32_bf16(a1, g1, acc2[t], 0, 0, 0);
            }
        }
        __syncthreads();
    }

    const int r0 = bm + w * 16 + quad * 4;
    if (mode == 2) {
        const int kvh = cx;
        #pragma unroll
        for (int t = 0; t < 4; ++t) {
            const int d = t * 16 + lm;
            const int half = d >> 5, d32 = d & 31;
            #pragma unroll
            for (int i = 0; i < 4; ++i) {
                const int s = r0 + i;
                float val = acc[t][i] / (1.0f + __expf(-acc2[t][i]));
                const size_t vi = (((((size_t)(kvh*2 + half)*64 + (s>>5))*2 + (d32>>4))*64)
                                   + ((s&31)>>3)*16 + (d32&15))*8 + (s&7);
                Vpk[vi] = __float2bfloat16(val);
            }
        }
    } else {
        const float gain = (mode == 0) ? qgain[cx - 8] : 1.0f;
        float rr[4];
        #pragma unroll
        for (int i = 0; i < 4; ++i) {
            float v0 = acc[0][i] * acc[0][i] + acc[2][i] * acc[2][i];
            float v1 = acc[1][i] * acc[1][i] + acc[3][i] * acc[3][i];
            float ssv = v0 + v1;
            ssv += __shfl_xor(ssv, 8);
            ssv += __shfl_xor(ssv, 4);
            ssv += __shfl_xor(ssv, 2);
            ssv += __shfl_xor(ssv, 1);
            rr[i] = rsqrtf(ssv * (1.0f/64.0f) + 1.1920928955078125e-7f);
        }
        #pragma unroll
        for (int t = 0; t < 4; ++t) {
            const int d = t * 16 + lm;
            #pragma unroll
            for (int i = 0; i < 4; ++i) {
                const int s = r0 + i;
                float n  = acc[t][i]     * rr[i];
                float no = acc[t ^ 2][i] * rr[i];
                const int ri = s * 32 + (d & 31);
                float c = rc[ri], sn = rs[ri];
                float val = (t < 2) ? (n * c + no * sn) * gain
                                    : (n * c + -no * sn) * gain;
                if (mode == 0) {
                    Qb[(size_t)s * DIM + (cx - 8) * 64 + d] = __float2bfloat16(val);
                } else {
                    const int kvh = cx - 4;
                    const int half = d >> 5, d32 = d & 31;
                    const size_t ki = (((((size_t)(kvh*2 + half)*64 + (s>>5))*2 + ((s&31)>>4))*64)
                                       + (d32>>3)*16 + (s&15))*8 + (d32&7);
                    Kpk[ki] = __float2bfloat16(val);
                }
            }
        }
    }
}

// ---------------------------------------------------------------------------
// MFMA flash attention v5c: R8-verified structure (4-wave k-split, LDS P
// round-trip, mask skip, setprio, linear merge) + rotating-register K
// prefetch (R4-proven pattern). The per-iteration "memory"-clobbered asm
// prevents the compiler from hoisting next-tile K loads, so without the
// explicit prefetch the QK MFMAs eat the full L2 latency on their K
// fragments every iteration. K-only (+8 VGPRs) to stay in the (256,8)
// 64-VGPR budget; V loads already issue ~40+ cy before their use.
// ---------------------------------------------------------------------------
__global__ __launch_bounds__(256, 8) void attn_mfma(
    const bf16* __restrict__ Qb, const bf16* __restrict__ Kpk,
    const bf16* __restrict__ Vpk, bf16* __restrict__ Yab) {
    __shared__ short PW[4][640];          // per-wave P round-trip buffers
    __shared__ float RED[3][64][13];      // waves 1-3 partials (padded rows)
    const int id    = blockIdx.x;
    const int qtile = 127 - (id >> 5);    // heavy first
    const int hh    = id & 31;
    const int h     = hh >> 1;
    const int half  = hh & 1;
    const int kvh   = h >> 2;
    const int tid   = threadIdx.x;
    const int wid   = tid >> 6;
    const int lane  = tid & 63;
    const int quad  = lane >> 4;
    const int m     = lane & 15;
    bf16* PWb = (bf16*)PW[wid];

    const int qrow = qtile * 16 + m;
    short8 qf = *(const short8*)(Qb + (size_t)qrow * DIM + h * HD + half * 32 + quad * 8);

    const bf16* kbase = Kpk + (size_t)(kvh * 2 + half) * 64 * 1024 + lane * 8;
    const bf16* vbase = Vpk + (size_t)(kvh * 2 + half) * 64 * 1024 + lane * 8;

    f32x4 o0 = {}, o1 = {};
    float lpart[4] = {0.f, 0.f, 0.f, 0.f};
    const float scale = 0.17677669529663687f;   // 1/sqrt(32)
    const int rbase = qtile * 16 + quad * 4;
    const int nkt = (qtile >> 1) + 1;

    short8 kf0 = {}, kf1 = {};
    if (wid < nkt) {                       // prologue K load for first tile
        kf0 = *(const short8*)(kbase + wid * 1024);
        kf1 = *(const short8*)(kbase + wid * 1024 + 512);
    }

    for (int kb = wid; kb < nkt; kb += 4) {
        const int kn = (kb + 4 < nkt) ? kb + 4 : kb;   // clamped prefetch
        short8 nk0 = *(const short8*)(kbase + kn * 1024);
        short8 nk1 = *(const short8*)(kbase + kn * 1024 + 512);

        f32x4 s0 = {}, s1 = {};
        __builtin_amdgcn_s_setprio(1);
        s0 = __builtin_amdgcn_mfma_f32_16x16x32_bf16(qf, kf0, s0, 0, 0, 0);
        s1 = __builtin_amdgcn_mfma_f32_16x16x32_bf16(qf, kf1, s1, 0, 0, 0);
        __builtin_amdgcn_s_setprio(0);
        short8 vt0 = *(const short8*)(vbase + kb * 1024);
        short8 vt1 = *(const short8*)(vbase + kb * 1024 + 512);

        float p0v[4], p1v[4];
        if (kb * 32 + 31 <= qtile * 16) {           // fully unmasked tile
            #pragma unroll
            for (int r = 0; r < 4; ++r) {
                p0v[r] = __expf(s0[r] * scale);
                p1v[r] = __expf(s1[r] * scale);
            }
        } else {                                    // diagonal straddle
            const int kg = kb * 32 + m;
            #pragma unroll
            for (int r = 0; r < 4; ++r) {
                const int rg = rbase + r;
                p0v[r] = (kg > rg)      ? 0.f : __expf(s0[r] * scale);
                p1v[r] = (kg + 16 > rg) ? 0.f : __expf(s1[r] * scale);
            }
        }
        #pragma unroll
        for (int r = 0; r < 4; ++r) {
            lpart[r] += p0v[r] + p1v[r];
            PWb[(quad * 4 + r) * 40 + m]      = __float2bfloat16(p0v[r]);
            PWb[(quad * 4 + r) * 40 + 16 + m] = __float2bfloat16(p1v[r]);
        }
        asm volatile("s_waitcnt lgkmcnt(0)" ::: "memory");
        short8 pf = *(const short8*)&PW[wid][m * 40 + quad * 8];
        __builtin_amdgcn_s_setprio(1);
        o0 = __builtin_amdgcn_mfma_f32_16x16x32_bf16(pf, vt0, o0, 0, 0, 0);
        o1 = __builtin_amdgcn_mfma_f32_16x16x32_bf16(pf, vt1, o1, 0, 0, 0);
        __builtin_amdgcn_s_setprio(0);
        kf0 = nk0; kf1 = nk1;
    }

    // cross-wave merge: waves 1-3 park partials; wave 0 reduces + writes.
    if (wid > 0) {
        float* rp = &RED[wid - 1][lane][0];
        #pragma unroll
        for (int r = 0; r < 4; ++r) {
            rp[r]     = o0[r];
            rp[4 + r] = o1[r];
            rp[8 + r] = lpart[r];
        }
    }
    __syncthreads();
    if (wid == 0) {
        #pragma unroll
        for (int wv = 0; wv < 3; ++wv) {
            const float* rp = &RED[wv][lane][0];
            #pragma unroll
            for (int r = 0; r < 4; ++r) {
                o0[r]     += rp[r];
                o1[r]     += rp[4 + r];
                lpart[r]  += rp[8 + r];
            }
        }
        #pragma unroll
        for (int r = 0; r < 4; ++r) {
            float v = lpart[r];
            v += __shfl_xor(v, 1);
            v += __shfl_xor(v, 2);
            v += __shfl_xor(v, 4);
            v += __shfl_xor(v, 8);
            lpart[r] = 1.f / v;
        }
        #pragma unroll
        for (int r = 0; r < 4; ++r) {
            bf16* op = Yab + (size_t)(rbase + r) * DIM + h * HD + half * 32;
            op[m]      = __float2bfloat16(o0[r] * lpart[r]);
            op[16 + m] = __float2bfloat16(o1[r] * lpart[r]);
        }
    }
}

// ---------------------------------------------------------------------------
// Workspace (31.5 MB):
//  0-4    Qb bf16 (step1 w, step2 r)
//  8-9    Kpk bf16 | 9-10 Vpk bf16 (step1 w, step2 r)
//  14-14.5 rc/rs rotary table (step0 w, step1 r; dead after)
//  14-18  Yab bf16 attn out, a_raw layout (step2 w, step3 r; overlays rc/rs)
//  22-26  xb bf16 (step0 w, step1 r)
//  26-28  Wqb | 28-28.5 Wkb | 28.5-29 Wvb | 29-29.5 Wgb | 29.5-31.5 Wob'
// ---------------------------------------------------------------------------
extern "C" void kernel_launch(void* const* d_in, const int* in_sizes, int n_in,
                              void* d_out, int out_size, void* d_ws, size_t ws_size,
                              hipStream_t stream) {
    const float* x  = (const float*)d_in[0];
    const float* Wq = (const float*)d_in[1];
    const float* Wk = (const float*)d_in[2];
    const float* Wv = (const float*)d_in[3];
    const float* Wg = (const float*)d_in[4];
    const float* Wo = (const float*)d_in[5];
    const float* qg = (const float*)d_in[6];
    const float* lp = (const float*)d_in[7];
    float* out = (float*)d_out;

    char* ws = (char*)d_ws;
    bf16* Qb   = (bf16*)ws;
    bf16* Kpk  = (bf16*)(ws + (8u << 20));
    bf16* Vpk  = (bf16*)(ws + (9u << 20));
    float* rc  = (float*)(ws + (14u << 20));
    float* rs  = (float*)(ws + (14u << 20) + (256u << 10));
    bf16* Yab  = (bf16*)(ws + (14u << 20));    // overlays dead rc/rs
    bf16* xb   = (bf16*)(ws + (22u << 20));
    bf16* Wqb  = (bf16*)(ws + (26u << 20));
    bf16* Wkb  = (bf16*)(ws + (28u << 20));
    bf16* Wvb  = (bf16*)(ws + (28u << 20) + (512u << 10));
    bf16* Wgb  = (bf16*)(ws + (29u << 20));
    bf16* Wob  = (bf16*)(ws + (29u << 20) + (512u << 10));

    // 0. Cast inputs to bf16 + combine-folded Wo' + rotary table
    cast6<<<dim3(512, 7), 256, 0, stream>>>(x, Wq, Wk, Wv, Wg, Wo,
                                            xb, Wqb, Wkb, Wvb, Wgb, Wob,
                                            rc, rs, lp);

    // 1. Fused Q/K/V/G projection + epilogue (R8-verified)
    gemm_qkvg_post<<<dim3(24, S_LEN/64), 256, 0, stream>>>(
        xb, Wqb, Wkb, Wvb, Wgb, Qb, Kpk, Vpk, qg, rc, rs);

    // 2. MFMA flash attention (R8 structure + K register prefetch)
    attn_mfma<<<4096, 256, 0, stream>>>(Qb, Kpk, Vpk, Yab);

    // 3. Combine-folded output projection (R8-verified)
    gemm_out<<<dim3(DIM/64, S_LEN/64), 256, 0, stream>>>(Yab, Wob, out);
}

// Round 11
// 128.747 us; speedup vs baseline: 1.0683x; 1.0626x over previous
//
#include <hip/hip_runtime.h>
#include <hip/hip_bf16.h>
#include <math.h>

#define S_LEN 2048
#define DIM   1024
#define NH    16
#define NKVH  4
#define HD    64
#define KVDIM 256

typedef __hip_bfloat16 bf16;
typedef __attribute__((ext_vector_type(8))) short short8;   // 8 bf16 (4 VGPRs)
typedef __attribute__((ext_vector_type(4))) float f32x4;

#define GLOBAL_AS __attribute__((address_space(1)))
#define LDS_AS    __attribute__((address_space(3)))

__device__ __forceinline__ void gload_lds16(const bf16* g, bf16* l) {
    // LDS dest = wave-uniform base + lane*16 (hardware rule).
    __builtin_amdgcn_global_load_lds((const GLOBAL_AS void*)g, (LDS_AS void*)l,
                                     16, 0, 0);
}

// ---------------------------------------------------------------------------
// fp32 -> bf16 cast of inputs (grid.y = which). Slice 5 builds the
// COMBINE-FOLDED output weight Wo' (lambda absorbed):
//   Wo'[n, h*64+d]    = Wo[n,h*64+d] + Wo[n,h*64+32+d]        (a1 slot)
//   Wo'[n, h*64+32+d] = lam_h*(Wo[n,h*64+32+d] - Wo[n,h*64+d]) (a2 slot)
// Slice 6 builds the rotary cos/sin table (bit-identical math).
// ---------------------------------------------------------------------------
__global__ __launch_bounds__(256) void cast6(
    const float* __restrict__ x,  const float* __restrict__ Wq,
    const float* __restrict__ Wk, const float* __restrict__ Wv,
    const float* __restrict__ Wg, const float* __restrict__ Wo,
    bf16* __restrict__ xb,  bf16* __restrict__ Wqb,
    bf16* __restrict__ Wkb, bf16* __restrict__ Wvb,
    bf16* __restrict__ Wgb, bf16* __restrict__ Wob,
    float* __restrict__ rc, float* __restrict__ rs,
    const float* __restrict__ lp) {
    if (blockIdx.y == 6) {
        const int idx = blockIdx.x * 256 + threadIdx.x;
        if (idx < S_LEN * 32) {
            const int s = idx >> 5, i = idx & 31;
            float af  = (float)(((double)(2 * i) / 64.0) * 3.14159265358979323846);
            float ang = (float)s * af;
            float radius = 1.0f / (1.0f + 0.01f * (float)s);
            rc[idx] = radius * (float)cos((double)ang);
            rs[idx] = radius * (float)sin((double)ang);
        }
        return;
    }
    if (blockIdx.y == 5) {                 // Wo' build (combine folded)
        for (int i = (blockIdx.x * 256 + threadIdx.x) * 4; i < DIM * DIM;
             i += gridDim.x * 1024) {
            const int n = i >> 10, c = i & (DIM - 1);
            const int h = c >> 6, half = (c >> 5) & 1, d = c & 31;
            const float* base = Wo + (size_t)n * DIM + h * 64 + d;
            float4 w1 = *(const float4*)(base);
            float4 w2 = *(const float4*)(base + 32);
            const float lam = lp[h];
            float4 r;
            if (half == 0) {
                r.x = w1.x + w2.x; r.y = w1.y + w2.y;
                r.z = w1.z + w2.z; r.w = w1.w + w2.w;
            } else {
                r.x = lam * (w2.x - w1.x); r.y = lam * (w2.y - w1.y);
                r.z = lam * (w2.z - w1.z); r.w = lam * (w2.w - w1.w);
            }
            Wob[i]     = __float2bfloat16(r.x);
            Wob[i + 1] = __float2bfloat16(r.y);
            Wob[i + 2] = __float2bfloat16(r.z);
            Wob[i + 3] = __float2bfloat16(r.w);
        }
        return;
    }
    const float* s; bf16* d; int n;
    switch (blockIdx.y) {
        case 0: s = x;  d = xb;  n = S_LEN * DIM; break;
        case 1: s = Wq; d = Wqb; n = DIM * DIM;   break;
        case 2: s = Wk; d = Wkb; n = KVDIM * DIM; break;
        case 3: s = Wv; d = Wvb; n = KVDIM * DIM; break;
        default: s = Wg; d = Wgb; n = KVDIM * DIM; break;
    }
    for (int i = (blockIdx.x * 256 + threadIdx.x) * 4; i < n; i += gridDim.x * 1024) {
        float4 v = *(const float4*)(s + i);
        d[i]     = __float2bfloat16(v.x);
        d[i + 1] = __float2bfloat16(v.y);
        d[i + 2] = __float2bfloat16(v.z);
        d[i + 3] = __float2bfloat16(v.w);
    }
}

// ---------------------------------------------------------------------------
// R5-verified 64x64 GEMM core (single-buffered; gload_lds staging; XOR
// swizzle both sides). GEMM structure is FROZEN: R2/R6/R9 all showed larger
// tiles / dbuf lose to occupancy at this problem size (m102 plateau).
// ---------------------------------------------------------------------------
__device__ __forceinline__ void gemm_core(
    const bf16* __restrict__ A, const bf16* __restrict__ B,
    float* __restrict__ C, int bm, int bn, int N, int K) {
    __shared__ bf16 As[64 * 64];
    __shared__ bf16 Bs[64 * 64];
    const int tid  = threadIdx.x;
    const int w    = tid >> 6;
    const int lane = tid & 63;
    const int quad = lane >> 4;
    const int lm   = lane & 15;
    const int srow = tid >> 3;
    const int sseg = (tid & 7) ^ (srow & 7);
    const bf16* a0p = A + (size_t)(bm + srow) * K + (sseg << 3);
    const bf16* a1p = a0p + (size_t)32 * K;
    const bf16* b0p = B + (size_t)(bn + srow) * K + (sseg << 3);
    const bf16* b1p = b0p + (size_t)32 * K;
    bf16* ldsA = As + w * 512;
    bf16* ldsB = Bs + w * 512;

    f32x4 acc[4] = {};
    const int ra  = w * 16 + lm;
    const int rax = ra & 7;
    const int aoff0 = ra * 64 + (((quad    ) ^ rax) << 3);
    const int aoff1 = ra * 64 + (((quad + 4) ^ rax) << 3);
    const int rbx = lm & 7;
    const int boff0 = lm * 64 + (((quad    ) ^ rbx) << 3);
    const int boff1 = lm * 64 + (((quad + 4) ^ rbx) << 3);

    for (int k0 = 0; k0 < K; k0 += 64) {
        gload_lds16(a0p + k0, ldsA);
        gload_lds16(a1p + k0, ldsA + 2048);
        gload_lds16(b0p + k0, ldsB);
        gload_lds16(b1p + k0, ldsB + 2048);
        __syncthreads();
        short8 a0 = *(const short8*)&As[aoff0];
        short8 a1 = *(const short8*)&As[aoff1];
        #pragma unroll
        for (int t = 0; t < 4; ++t) {
            short8 b0 = *(const short8*)&Bs[boff0 + t * 16 * 64];
            short8 b1 = *(const short8*)&Bs[boff1 + t * 16 * 64];
            acc[t] = __builtin_amdgcn_mfma_f32_16x16x32_bf16(a0, b0, acc[t], 0, 0, 0);
            acc[t] = __builtin_amdgcn_mfma_f32_16x16x32_bf16(a1, b1, acc[t], 0, 0, 0);
        }
        __syncthreads();
    }
    const int r0 = bm + w * 16 + quad * 4;
    #pragma unroll
    for (int t = 0; t < 4; ++t) {
        const int col = bn + t * 16 + lm;
        #pragma unroll
        for (int i = 0; i < 4; ++i)
            C[(size_t)(r0 + i) * N + col] = acc[t][i];
    }
}

__global__ __launch_bounds__(256) void gemm_out(
    const bf16* __restrict__ Yb, const bf16* __restrict__ Wob,
    float* __restrict__ C) {
    gemm_core(Yb, Wob, C, blockIdx.y * 64, blockIdx.x * 64, DIM, DIM);
}

// ---------------------------------------------------------------------------
// FUSED Q/K/V/G projection + postproc (R3/R5/R8-verified single-buffer core).
// grid.x: 0-3 VG (heavy first), 4-7 K, 8-23 Q.
// ---------------------------------------------------------------------------
__global__ __launch_bounds__(256) void gemm_qkvg_post(
    const bf16* __restrict__ xb,  const bf16* __restrict__ Wqb,
    const bf16* __restrict__ Wkb, const bf16* __restrict__ Wvb,
    const bf16* __restrict__ Wgb,
    bf16* __restrict__ Qb, bf16* __restrict__ Kpk, bf16* __restrict__ Vpk,
    const float* __restrict__ qgain,
    const float* __restrict__ rc, const float* __restrict__ rs) {
    __shared__ bf16 As[64 * 64];
    __shared__ bf16 Bs[64 * 64];
    __shared__ bf16 Gs[64 * 64];
    const int cx = blockIdx.x;
    const int bm = blockIdx.y * 64;
    const int tid  = threadIdx.x;
    const int w    = tid >> 6;
    const int lane = tid & 63;
    const int quad = lane >> 4;
    const int lm   = lane & 15;
    const int srow = tid >> 3;
    const int sseg = (tid & 7) ^ (srow & 7);

    int mode, bn;                       // 0=Q, 1=K, 2=VG (block-uniform)
    const bf16 *B0, *B1;
    if (cx < 4)      { mode = 2; bn = cx * 64;        B0 = Wvb; B1 = Wgb; }
    else if (cx < 8) { mode = 1; bn = (cx - 4) * 64;  B0 = Wkb; B1 = Wkb; }
    else             { mode = 0; bn = (cx - 8) * 64;  B0 = Wqb; B1 = Wqb; }

    const bf16* a0p = xb + (size_t)(bm + srow) * DIM + (sseg << 3);
    const bf16* a1p = a0p + (size_t)32 * DIM;
    const bf16* b0p = B0 + (size_t)(bn + srow) * DIM + (sseg << 3);
    const bf16* b1p = b0p + (size_t)32 * DIM;
    const bf16* g0p = B1 + (size_t)(bn + srow) * DIM + (sseg << 3);
    const bf16* g1p = g0p + (size_t)32 * DIM;
    bf16* ldsA = As + w * 512;
    bf16* ldsB = Bs + w * 512;
    bf16* ldsG = Gs + w * 512;

    f32x4 acc[4]  = {};
    f32x4 acc2[4] = {};
    const int ra  = w * 16 + lm;
    const int rax = ra & 7;
    const int aoff0 = ra * 64 + (((quad    ) ^ rax) << 3);
    const int aoff1 = ra * 64 + (((quad + 4) ^ rax) << 3);
    const int rbx = lm & 7;
    const int boff0 = lm * 64 + (((quad    ) ^ rbx) << 3);
    const int boff1 = lm * 64 + (((quad + 4) ^ rbx) << 3);

    for (int k0 = 0; k0 < DIM; k0 += 64) {
        gload_lds16(a0p + k0, ldsA);
        gload_lds16(a1p + k0, ldsA + 2048);
        gload_lds16(b0p + k0, ldsB);
        gload_lds16(b1p + k0, ldsB + 2048);
        if (mode == 2) {
            gload_lds16(g0p + k0, ldsG);
            gload_lds16(g1p + k0, ldsG + 2048);
        }
        __syncthreads();
        short8 a0 = *(const short8*)&As[aoff0];
        short8 a1 = *(const short8*)&As[aoff1];
        #pragma unroll
        for (int t = 0; t < 4; ++t) {
            short8 b0 = *(const short8*)&Bs[boff0 + t * 16 * 64];
            short8 b1 = *(const short8*)&Bs[boff1 + t * 16 * 64];
            acc[t] = __builtin_amdgcn_mfma_f32_16x16x32_bf16(a0, b0, acc[t], 0, 0, 0);
            acc[t] = __builtin_amdgcn_mfma_f32_16x16x32_bf16(a1, b1, acc[t], 0, 0, 0);
        }
        if (mode == 2) {
            #pragma unroll
            for (int t = 0; t < 4; ++t) {
                short8 g0 = *(const short8*)&Gs[boff0 + t * 16 * 64];
                short8 g1 = *(const short8*)&Gs[boff1 + t * 16 * 64];
                acc2[t] = __builtin_amdgcn_mfma_f32_16x16x32_bf16(a0, g0, acc2[t], 0, 0, 0);
                acc2[t] = __builtin_amdgcn_mfma_f32_16x16x32_bf16(a1, g1, acc2[t], 0, 0, 0);
            }
        }
        __syncthreads();
    }

    const int r0 = bm + w * 16 + quad * 4;
    if (mode == 2) {
        const int kvh = cx;
        #pragma unroll
        for (int t = 0; t < 4; ++t) {
            const int d = t * 16 + lm;
            const int half = d >> 5, d32 = d & 31;
            #pragma unroll
            for (int i = 0; i < 4; ++i) {
                const int s = r0 + i;
                float val = acc[t][i] / (1.0f + __expf(-acc2[t][i]));
                const size_t vi = (((((size_t)(kvh*2 + half)*64 + (s>>5))*2 + (d32>>4))*64)
                                   + ((s&31)>>3)*16 + (d32&15))*8 + (s&7);
                Vpk[vi] = __float2bfloat16(val);
            }
        }
    } else {
        const float gain = (mode == 0) ? qgain[cx - 8] : 1.0f;
        float rr[4];
        #pragma unroll
        for (int i = 0; i < 4; ++i) {
            float v0 = acc[0][i] * acc[0][i] + acc[2][i] * acc[2][i];
            float v1 = acc[1][i] * acc[1][i] + acc[3][i] * acc[3][i];
            float ssv = v0 + v1;
            ssv += __shfl_xor(ssv, 8);
            ssv += __shfl_xor(ssv, 4);
            ssv += __shfl_xor(ssv, 2);
            ssv += __shfl_xor(ssv, 1);
            rr[i] = rsqrtf(ssv * (1.0f/64.0f) + 1.1920928955078125e-7f);
        }
        #pragma unroll
        for (int t = 0; t < 4; ++t) {
            const int d = t * 16 + lm;
            #pragma unroll
            for (int i = 0; i < 4; ++i) {
                const int s = r0 + i;
                float n  = acc[t][i]     * rr[i];
                float no = acc[t ^ 2][i] * rr[i];
                const int ri = s * 32 + (d & 31);
                float c = rc[ri], sn = rs[ri];
                float val = (t < 2) ? (n * c + no * sn) * gain
                                    : (n * c + -no * sn) * gain;
                if (mode == 0) {
                    Qb[(size_t)s * DIM + (cx - 8) * 64 + d] = __float2bfloat16(val);
                } else {
                    const int kvh = cx - 4;
                    const int half = d >> 5, d32 = d & 31;
                    const size_t ki = (((((size_t)(kvh*2 + half)*64 + (s>>5))*2 + ((s&31)>>4))*64)
                                       + (d32>>3)*16 + (s&15))*8 + (d32&7);
                    Kpk[ki] = __float2bfloat16(val);
                }
            }
        }
    }
}

// ---------------------------------------------------------------------------
// MFMA flash attention v5b (R8-verified): 4-wave k-split, LDS P round-trip,
// tile-uniform mask skip, setprio around MFMA pairs, linear merge.
// R10's K register prefetch REVERTED (regressed: +16 live VGPRs inside the
// (256,8) 64-VGPR envelope -> spill/pressure loss > latency win).
// ---------------------------------------------------------------------------
__global__ __launch_bounds__(256, 8) void attn_mfma(
    const bf16* __restrict__ Qb, const bf16* __restrict__ Kpk,
    const bf16* __restrict__ Vpk, bf16* __restrict__ Yab) {
    __shared__ short PW[4][640];          // per-wave P round-trip buffers
    __shared__ float RED[3][64][13];      // waves 1-3 partials (padded rows)
    const int id    = blockIdx.x;
    const int qtile = 127 - (id >> 5);    // heavy first
    const int hh    = id & 31;
    const int h     = hh >> 1;
    const int half  = hh & 1;
    const int kvh   = h >> 2;
    const int tid   = threadIdx.x;
    const int wid   = tid >> 6;
    const int lane  = tid & 63;
    const int quad  = lane >> 4;
    const int m     = lane & 15;
    bf16* PWb = (bf16*)PW[wid];

    const int qrow = qtile * 16 + m;
    short8 qf = *(const short8*)(Qb + (size_t)qrow * DIM + h * HD + half * 32 + quad * 8);

    const bf16* kbase = Kpk + (size_t)(kvh * 2 + half) * 64 * 1024 + lane * 8;
    const bf16* vbase = Vpk + (size_t)(kvh * 2 + half) * 64 * 1024 + lane * 8;

    f32x4 o0 = {}, o1 = {};
    float lpart[4] = {0.f, 0.f, 0.f, 0.f};
    const float scale = 0.17677669529663687f;   // 1/sqrt(32)
    const int rbase = qtile * 16 + quad * 4;
    const int nkt = (qtile >> 1) + 1;

    for (int kb = wid; kb < nkt; kb += 4) {
        short8 kf0 = *(const short8*)(kbase + kb * 1024);
        short8 kf1 = *(const short8*)(kbase + kb * 1024 + 512);
        f32x4 s0 = {}, s1 = {};
        __builtin_amdgcn_s_setprio(1);
        s0 = __builtin_amdgcn_mfma_f32_16x16x32_bf16(qf, kf0, s0, 0, 0, 0);
        s1 = __builtin_amdgcn_mfma_f32_16x16x32_bf16(qf, kf1, s1, 0, 0, 0);
        __builtin_amdgcn_s_setprio(0);
        short8 vt0 = *(const short8*)(vbase + kb * 1024);
        short8 vt1 = *(const short8*)(vbase + kb * 1024 + 512);

        float p0v[4], p1v[4];
        if (kb * 32 + 31 <= qtile * 16) {           // fully unmasked tile
            #pragma unroll
            for (int r = 0; r < 4; ++r) {
                p0v[r] = __expf(s0[r] * scale);
                p1v[r] = __expf(s1[r] * scale);
            }
        } else {                                    // diagonal straddle
            const int kg = kb * 32 + m;
            #pragma unroll
            for (int r = 0; r < 4; ++r) {
                const int rg = rbase + r;
                p0v[r] = (kg > rg)      ? 0.f : __expf(s0[r] * scale);
                p1v[r] = (kg + 16 > rg) ? 0.f : __expf(s1[r] * scale);
            }
        }
        #pragma unroll
        for (int r = 0; r < 4; ++r) {
            lpart[r] += p0v[r] + p1v[r];
            PWb[(quad * 4 + r) * 40 + m]      = __float2bfloat16(p0v[r]);
            PWb[(quad * 4 + r) * 40 + 16 + m] = __float2bfloat16(p1v[r]);
        }
        asm volatile("s_waitcnt lgkmcnt(0)" ::: "memory");
        short8 pf = *(const short8*)&PW[wid][m * 40 + quad * 8];
        __builtin_amdgcn_s_setprio(1);
        o0 = __builtin_amdgcn_mfma_f32_16x16x32_bf16(pf, vt0, o0, 0, 0, 0);
        o1 = __builtin_amdgcn_mfma_f32_16x16x32_bf16(pf, vt1, o1, 0, 0, 0);
        __builtin_amdgcn_s_setprio(0);
    }

    // cross-wave merge: waves 1-3 park partials; wave 0 reduces + writes.
    if (wid > 0) {
        float* rp = &RED[wid - 1][lane][0];
        #pragma unroll
        for (int r = 0; r < 4; ++r) {
            rp[r]     = o0[r];
            rp[4 + r] = o1[r];
            rp[8 + r] = lpart[r];
        }
    }
    __syncthreads();
    if (wid == 0) {
        #pragma unroll
        for (int wv = 0; wv < 3; ++wv) {
            const float* rp = &RED[wv][lane][0];
            #pragma unroll
            for (int r = 0; r < 4; ++r) {
                o0[r]     += rp[r];
                o1[r]     += rp[4 + r];
                lpart[r]  += rp[8 + r];
            }
        }
        #pragma unroll
        for (int r = 0; r < 4; ++r) {
            float v = lpart[r];
            v += __shfl_xor(v, 1);
            v += __shfl_xor(v, 2);
            v += __shfl_xor(v, 4);
            v += __shfl_xor(v, 8);
            lpart[r] = 1.f / v;
        }
        #pragma unroll
        for (int r = 0; r < 4; ++r) {
            bf16* op = Yab + (size_t)(rbase + r) * DIM + h * HD + half * 32;
            op[m]      = __float2bfloat16(o0[r] * lpart[r]);
            op[16 + m] = __float2bfloat16(o1[r] * lpart[r]);
        }
    }
}

// ---------------------------------------------------------------------------
// Workspace (31.5 MB):
//  0-4    Qb bf16 (step1 w, step2 r)
//  8-9    Kpk bf16 | 9-10 Vpk bf16 (step1 w, step2 r)
//  14-14.5 rc/rs rotary table (step0 w, step1 r; dead after)
//  14-18  Yab bf16 attn out, a_raw layout (step2 w, step3 r; overlays rc/rs)
//  22-26  xb bf16 (step0 w, step1 r)
//  26-28  Wqb | 28-28.5 Wkb | 28.5-29 Wvb | 29-29.5 Wgb | 29.5-31.5 Wob'
// ---------------------------------------------------------------------------
extern "C" void kernel_launch(void* const* d_in, const int* in_sizes, int n_in,
                              void* d_out, int out_size, void* d_ws, size_t ws_size,
                              hipStream_t stream) {
    const float* x  = (const float*)d_in[0];
    const float* Wq = (const float*)d_in[1];
    const float* Wk = (const float*)d_in[2];
    const float* Wv = (const float*)d_in[3];
    const float* Wg = (const float*)d_in[4];
    const float* Wo = (const float*)d_in[5];
    const float* qg = (const float*)d_in[6];
    const float* lp = (const float*)d_in[7];
    float* out = (float*)d_out;

    char* ws = (char*)d_ws;
    bf16* Qb   = (bf16*)ws;
    bf16* Kpk  = (bf16*)(ws + (8u << 20));
    bf16* Vpk  = (bf16*)(ws + (9u << 20));
    float* rc  = (float*)(ws + (14u << 20));
    float* rs  = (float*)(ws + (14u << 20) + (256u << 10));
    bf16* Yab  = (bf16*)(ws + (14u << 20));    // overlays dead rc/rs
    bf16* xb   = (bf16*)(ws + (22u << 20));
    bf16* Wqb  = (bf16*)(ws + (26u << 20));
    bf16* Wkb  = (bf16*)(ws + (28u << 20));
    bf16* Wvb  = (bf16*)(ws + (28u << 20) + (512u << 10));
    bf16* Wgb  = (bf16*)(ws + (29u << 20));
    bf16* Wob  = (bf16*)(ws + (29u << 20) + (512u << 10));

    // 0. Cast inputs to bf16 + combine-folded Wo' + rotary table
    cast6<<<dim3(512, 7), 256, 0, stream>>>(x, Wq, Wk, Wv, Wg, Wo,
                                            xb, Wqb, Wkb, Wvb, Wgb, Wob,
                                            rc, rs, lp);

    // 1. Fused Q/K/V/G projection + epilogue (R8-verified)
    gemm_qkvg_post<<<dim3(24, S_LEN/64), 256, 0, stream>>>(
        xb, Wqb, Wkb, Wvb, Wgb, Qb, Kpk, Vpk, qg, rc, rs);

    // 2. MFMA flash attention (R8-verified)
    attn_mfma<<<4096, 256, 0, stream>>>(Qb, Kpk, Vpk, Yab);

    // 3. Combine-folded output projection (R8-verified)
    gemm_out<<<dim3(DIM/64, S_LEN/64), 256, 0, stream>>>(Yab, Wob, out);
}